// Round 1
// baseline (4480.663 us; speedup 1.0000x reference)
//
#include <hip/hip_runtime.h>
#include <math.h>

// ---------------- problem constants ----------------
#define NN 50000      // nodes
#define NE 150000     // edges
#define NG 2000       // graphs
#define DD 75         // node feature dim
#define NL 4          // layers
// TOWERS=5, F_OUT=15, T*F=75
#define AVG_DEG_LOG 1.1308269950720915f

// ---------------- preprocessing kernels ----------------
__global__ void k_deg(const int* __restrict__ dst, int* __restrict__ deg) {
  int e = blockIdx.x * 256 + threadIdx.x;
  if (e < NE) atomicAdd(&deg[dst[e]], 1);
}

// single-block exclusive scan of deg[0..NN) -> off[0..NN]
__global__ __launch_bounds__(1024) void k_scan(const int* __restrict__ deg, int* __restrict__ off) {
  __shared__ int wsum[16];
  __shared__ int wpre[16];
  __shared__ int carry_s;
  int tid = threadIdx.x, lane = tid & 63, wv = tid >> 6;
  if (tid == 0) carry_s = 0;
  __syncthreads();
  for (int base = 0; base < NN; base += 1024) {
    int i = base + tid;
    int v = (i < NN) ? deg[i] : 0;
    int incl = v;
    #pragma unroll
    for (int d = 1; d < 64; d <<= 1) { int t = __shfl_up(incl, d); if (lane >= d) incl += t; }
    if (lane == 63) wsum[wv] = incl;
    __syncthreads();
    if (wv == 0) {
      int s = (lane < 16) ? wsum[lane] : 0;
      int sc = s;
      #pragma unroll
      for (int d = 1; d < 16; d <<= 1) { int t = __shfl_up(sc, d); if (lane >= d) sc += t; }
      if (lane < 16) wpre[lane] = sc - s;
    }
    __syncthreads();
    int carry = carry_s;
    int excl = carry + wpre[wv] + incl - v;
    if (i < NN) off[i] = excl;
    __syncthreads();
    if (tid == 1023) carry_s = excl + v;
    __syncthreads();
  }
  if (tid == 0) off[NN] = carry_s;
}

// amp/invamp per node (deg is layer-invariant) + init cursor for csr fill
__global__ void k_amp(const int* __restrict__ deg, const int* __restrict__ off,
                      float* __restrict__ amp, float* __restrict__ invamp, int* __restrict__ cursor) {
  int n = blockIdx.x * 256 + threadIdx.x;
  if (n < NN) {
    int d = deg[n]; if (d < 1) d = 1;
    float a = logf((float)d + 1.0f) / AVG_DEG_LOG;
    amp[n] = a; invamp[n] = 1.0f / a;
    cursor[n] = off[n];
  }
}

__global__ void k_fill(const int* __restrict__ src, const int* __restrict__ dst,
                       const int* __restrict__ attr, int* __restrict__ cursor,
                       int* __restrict__ csrc, int* __restrict__ cattr) {
  int e = blockIdx.x * 256 + threadIdx.x;
  if (e < NE) {
    int d = dst[e];
    int p = atomicAdd(&cursor[d], 1);
    csrc[p] = src[e];
    cattr[p] = attr[e];
  }
}

__global__ void k_embed(const int* __restrict__ x, const float* __restrict__ emb, float* __restrict__ h) {
  int i = blockIdx.x * 256 + threadIdx.x;
  if (i < NN * DD) {
    int n = i / DD, c = i - (i / DD) * DD;
    h[i] = emb[x[n] * DD + c];
  }
}

// ---------------- weight prepack (runs every call; tiny) ----------------
// B1[l][k][o]  (75 x 750): o<375 -> src block (rows 75..149 of Wpre), o>=375 -> dst block (rows 0..74)
// bias1[l][o]: 0 for src half, bpre for dst half
// WX[l][c][o]  (75 x 75):  x-block of Wpost (rows 0..74), o = t*15+j
// WA[l][s][c][o] (3 x 300 x 75): s=0 agg (rows 75..374), s=1 agg*amp (375..674), s=2 agg/amp (675..974)
__global__ void k_prepack(const float* __restrict__ Wpre, const float* __restrict__ bpre,
                          const float* __restrict__ Wpost,
                          float* __restrict__ B1, float* __restrict__ bias1,
                          float* __restrict__ WX, float* __restrict__ WA) {
  int i = blockIdx.x * 256 + threadIdx.x;
  const int SB1 = 4 * 75 * 750;
  const int SBias = SB1 + 4 * 750;
  const int SWX = SBias + 4 * 75 * 75;
  const int SWA = SWX + 4 * 3 * 300 * 75;
  if (i < SB1) {
    int l = i / (75 * 750); int rem = i - l * (75 * 750);
    int k = rem / 750, o = rem - (rem / 750) * 750;
    int oo = (o < 375) ? o : (o - 375);
    int t = oo / 75, f = oo - t * 75;
    int r = (o < 375) ? (75 + k) : k;
    B1[i] = Wpre[((l * 5 + t) * 225 + r) * 75 + f];
  } else if (i < SBias) {
    int j = i - SB1;
    int l = j / 750, o = j - l * 750;
    bias1[j] = (o < 375) ? 0.0f : bpre[l * 375 + (o - 375)];
  } else if (i < SWX) {
    int m = i - SBias;
    int l = m / (75 * 75); int rem = m - l * (75 * 75);
    int c = rem / 75, o = rem - (rem / 75) * 75;
    int t = o / 15, jj = o - t * 15;
    WX[m] = Wpost[((l * 5 + t) * 975 + c) * 15 + jj];
  } else if (i < SWA) {
    int m = i - SWX;
    int l = m / (3 * 300 * 75); int rem = m - l * (3 * 300 * 75);
    int s = rem / (300 * 75); rem -= s * (300 * 75);
    int c = rem / 75, o = rem - (rem / 75) * 75;
    int t = o / 15, jj = o - t * 15;
    int r = 75 + s * 300 + c;
    WA[m] = Wpost[((l * 5 + t) * 975 + r) * 15 + jj];
  }
}

// e_tab[l][a][tf] = (edge_emb[a] @ We[l] + be[l]) @ Wpre[l][t][150..224][f]   (4 attrs only!)
__global__ void k_etab(const float* __restrict__ edge_emb, const float* __restrict__ We,
                       const float* __restrict__ be, const float* __restrict__ Wpre,
                       float* __restrict__ etab) {
  __shared__ float ev[75];
  int l = blockIdx.x >> 2, a = blockIdx.x & 3;
  int tid = threadIdx.x;
  if (tid < 75) {
    float acc = be[l * 75 + tid];
    for (int k = 0; k < 50; ++k) acc += edge_emb[a * 50 + k] * We[(l * 50 + k) * 75 + tid];
    ev[tid] = acc;
  }
  __syncthreads();
  for (int tf = tid; tf < 375; tf += 256) {
    int t = tf / 75, f = tf - t * 75;
    float acc = 0.0f;
    for (int d = 0; d < 75; ++d) acc += ev[d] * Wpre[((l * 5 + t) * 225 + 150 + d) * 75 + f];
    etab[(l * 4 + a) * 375 + tf] = acc;
  }
}

// ---------------- GEMM1: [NN,75] @ [75,750] -> Hsrc[NN,375], Cdst[NN,375](+bpre) ----------------
__global__ __launch_bounds__(256) void k_gemm1(const float* __restrict__ h,
                                               const float* __restrict__ B1l,
                                               const float* __restrict__ bias1l,
                                               float* __restrict__ Hsrc, float* __restrict__ Cdst) {
  __shared__ float As[64][75];
  __shared__ float Bs[75][64];
  int tid = threadIdx.x;
  int tx = tid & 15, ty = tid >> 4;
  int m0 = blockIdx.y * 64;
  int n0 = blockIdx.x * 64;
  for (int idx = tid; idx < 64 * 75; idx += 256) {
    int r = idx / 75, k = idx - r * 75;
    int m = m0 + r;
    As[r][k] = (m < NN) ? h[(size_t)m * 75 + k] : 0.0f;
  }
  for (int idx = tid; idx < 75 * 64; idx += 256) {
    int r = idx >> 6, c = idx & 63;
    int n = n0 + c;
    Bs[r][c] = (n < 750) ? B1l[r * 750 + n] : 0.0f;
  }
  __syncthreads();
  float acc[4][4] = {};
  for (int k = 0; k < 75; ++k) {
    float a[4], b[4];
    #pragma unroll
    for (int i = 0; i < 4; ++i) a[i] = As[ty * 4 + i][k];
    #pragma unroll
    for (int j = 0; j < 4; ++j) b[j] = Bs[k][tx * 4 + j];
    #pragma unroll
    for (int i = 0; i < 4; ++i)
      #pragma unroll
      for (int j = 0; j < 4; ++j) acc[i][j] = fmaf(a[i], b[j], acc[i][j]);
  }
  #pragma unroll
  for (int i = 0; i < 4; ++i) {
    int m = m0 + ty * 4 + i;
    if (m >= NN) continue;
    #pragma unroll
    for (int j = 0; j < 4; ++j) {
      int n = n0 + tx * 4 + j;
      if (n >= 750) continue;
      float v = acc[i][j];
      if (n < 375) Hsrc[(size_t)m * 375 + n] = v;
      else Cdst[(size_t)m * 375 + (n - 375)] = v + bias1l[n];
    }
  }
}

// ---------------- fused aggregate + post_nn + lin ----------------
// per block: NT=8 nodes. A[n][1500] in LDS: (sum,sumsq,min,max) -> (mean,mn,mx,std), each [t*75+f].
#define NT 8
__global__ __launch_bounds__(256) void k_aggpost(
    const float* __restrict__ h, const float* __restrict__ Hsrc, const float* __restrict__ Cdst,
    const int* __restrict__ off, const int* __restrict__ csrc, const int* __restrict__ cattr,
    const float* __restrict__ etab_l, const float* __restrict__ WX_l, const float* __restrict__ WA_l,
    const float* __restrict__ bpost_l, const float* __restrict__ Wlin_l, const float* __restrict__ blin_l,
    const float* __restrict__ amp, const float* __restrict__ invamp,
    float* __restrict__ Zout) {
  __shared__ float A[NT][1500];
  __shared__ float hT[NT][75];
  __shared__ float P[NT][76];
  int tid = threadIdx.x;
  int n0 = blockIdx.x * NT;
  for (int idx = tid; idx < NT * 75; idx += 256) {
    int n = idx / 75, c = idx - n * 75;
    hT[n][c] = (n0 + n < NN) ? h[(size_t)(n0 + n) * 75 + c] : 0.0f;
  }
  for (int idx = tid; idx < NT * 375; idx += 256) {
    int n = idx / 375, c = idx - n * 375;
    A[n][c] = 0.0f;
    A[n][375 + c] = 0.0f;
    A[n][750 + c] = 3.402823466e+38f;
    A[n][1125 + c] = -3.402823466e+38f;
  }
  __syncthreads();
  int lane = tid & 63, wv = tid >> 6;
  for (int nl = wv; nl < NT; nl += 4) {
    int n = n0 + nl;
    if (n >= NN) break;
    int e0 = off[n], e1 = off[n + 1];
    for (int e = e0; e < e1; ++e) {
      int s = csrc[e], a = cattr[e];
      const float* hs = Hsrc + (size_t)s * 375;
      const float* et = etab_l + a * 375;
      #pragma unroll
      for (int ss = 0; ss < 6; ++ss) {
        int c = lane + ss * 64;
        if (c < 375) {
          float q = hs[c] + et[c];
          A[nl][c] += q;
          A[nl][375 + c] += q * q;
          A[nl][750 + c] = fminf(A[nl][750 + c], q);
          A[nl][1125 + c] = fmaxf(A[nl][1125 + c], q);
        }
      }
    }
  }
  __syncthreads();
  // finalize: (sum,sumsq,min,max) -> (mean,mn,mx,std); m = Cdst + q so offset adds to mean/mn/mx, cancels in std
  for (int idx = tid; idx < NT * 375; idx += 256) {
    int nl = idx / 375, c = idx - nl * 375;
    int n = n0 + nl;
    if (n < NN) {
      int d = off[n + 1] - off[n];
      float cd = Cdst[(size_t)n * 375 + c];
      float mean, mn, mx, sd;
      if (d > 0) {
        float inv = 1.0f / (float)d;
        float muq = A[nl][c] * inv;
        float var = fmaxf(A[nl][375 + c] * inv - muq * muq, 0.0f);
        mean = cd + muq;
        mn = cd + A[nl][750 + c];
        mx = cd + A[nl][1125 + c];
        sd = sqrtf(var + 1e-5f);
      } else {
        mean = 0.0f; mn = 0.0f; mx = 0.0f; sd = sqrtf(1e-5f);
      }
      A[nl][c] = mean; A[nl][375 + c] = mn; A[nl][750 + c] = mx; A[nl][1125 + c] = sd;
    }
  }
  __syncthreads();
  // post_nn: out[n][o] = bpost[o] + h@WX + A@W1 + amp*(A@W2) + invamp*(A@W3)
  for (int item = tid; item < 75 * NT; item += 256) {
    int n = item & (NT - 1);
    int o = item >> 3;
    int t = o / 15;
    float acc = bpost_l[o];
    for (int c = 0; c < 75; ++c) acc += hT[n][c] * WX_l[c * 75 + o];
    float a1 = 0.0f, a2 = 0.0f, a3 = 0.0f;
    #pragma unroll
    for (int k = 0; k < 4; ++k) {
      const float* Ak = &A[n][k * 375 + t * 75];
      const float* W1p = WA_l + (0 * 300 + k * 75) * 75 + o;
      const float* W2p = WA_l + (1 * 300 + k * 75) * 75 + o;
      const float* W3p = WA_l + (2 * 300 + k * 75) * 75 + o;
      for (int f = 0; f < 75; ++f) {
        float av = Ak[f];
        a1 = fmaf(av, W1p[f * 75], a1);
        a2 = fmaf(av, W2p[f * 75], a2);
        a3 = fmaf(av, W3p[f * 75], a3);
      }
    }
    int ng = n0 + n;
    float am = (ng < NN) ? amp[ng] : 1.0f;
    float iam = (ng < NN) ? invamp[ng] : 1.0f;
    P[n][o] = acc + a1 + am * a2 + iam * a3;
  }
  __syncthreads();
  // lin: Z = P @ Wlin + blin
  for (int item = tid; item < NT * 75; item += 256) {
    int n = item / 75, o = item - n * 75;
    int ng = n0 + n;
    if (ng < NN) {
      float acc = blin_l[o];
      for (int c = 0; c < 75; ++c) acc = fmaf(P[n][c], Wlin_l[c * 75 + o], acc);
      Zout[(size_t)ng * 75 + o] = acc;
    }
  }
}

// ---------------- batchnorm ----------------
#define BN_BLOCKS 96
#define BN_ROWS 521
__global__ __launch_bounds__(256) void k_bnstats(const float* __restrict__ Z, float* __restrict__ partial) {
  __shared__ float sArr[225];
  __shared__ float qArr[225];
  int tid = threadIdx.x;
  int r0 = blockIdx.x * BN_ROWS;
  int r1 = r0 + BN_ROWS; if (r1 > NN) r1 = NN;
  float s = 0.0f, q = 0.0f;
  if (tid < 225) {
    int rr = tid / 75, c = tid - rr * 75;
    for (int r = r0 + rr; r < r1; r += 3) {
      float v = Z[(size_t)r * 75 + c];
      s += v; q += v * v;
    }
    sArr[tid] = s; qArr[tid] = q;
  }
  __syncthreads();
  if (tid < 75) {
    float S = sArr[tid] + sArr[75 + tid] + sArr[150 + tid];
    float Q = qArr[tid] + qArr[75 + tid] + qArr[150 + tid];
    partial[blockIdx.x * 150 + tid] = S;
    partial[blockIdx.x * 150 + 75 + tid] = Q;
  }
}

__global__ void k_bnfinal(const float* __restrict__ partial, float* __restrict__ musig) {
  int c = threadIdx.x;
  if (c < 75) {
    float S = 0.0f, Q = 0.0f;
    for (int b = 0; b < BN_BLOCKS; ++b) { S += partial[b * 150 + c]; Q += partial[b * 150 + 75 + c]; }
    float mu = S * (1.0f / NN);
    float var = fmaxf(Q * (1.0f / NN) - mu * mu, 0.0f);
    musig[c] = mu;
    musig[75 + c] = 1.0f / sqrtf(var + 1e-5f);
  }
}

__global__ void k_bnapply(const float* __restrict__ Z, const float* __restrict__ musig,
                          const float* __restrict__ gamma_l, const float* __restrict__ beta_l,
                          float* __restrict__ hOut) {
  int i = blockIdx.x * 256 + threadIdx.x;
  if (i < NN * DD) {
    int c = i % 75;
    float v = (Z[i] - musig[c]) * musig[75 + c];
    hOut[i] = fmaxf(gamma_l[c] * v + beta_l[c], 0.0f);
  }
}

// ---------------- pool + MLP head ----------------
__global__ __launch_bounds__(128) void k_pool_mlp(const float* __restrict__ h, const int* __restrict__ batch,
                                                  const float* __restrict__ W1, const float* __restrict__ b1,
                                                  const float* __restrict__ W2, const float* __restrict__ b2,
                                                  const float* __restrict__ W3, const float* __restrict__ b3,
                                                  float* __restrict__ out) {
  __shared__ float pooled[75];
  __shared__ float z1[50];
  __shared__ float z2[25];
  __shared__ int se[2];
  int g = blockIdx.x, tid = threadIdx.x;
  if (tid < 2) {
    int target = g + tid;
    int lo = 0, hi = NN;
    while (lo < hi) { int mid = (lo + hi) >> 1; if (batch[mid] < target) lo = mid + 1; else hi = mid; }
    se[tid] = lo;
  }
  __syncthreads();
  int s = se[0], e = se[1];
  if (tid < 75) {
    float acc = 0.0f;
    for (int r = s; r < e; ++r) acc += h[(size_t)r * 75 + tid];
    pooled[tid] = acc;
  }
  __syncthreads();
  if (tid < 50) {
    float acc = b1[tid];
    for (int c = 0; c < 75; ++c) acc += pooled[c] * W1[c * 50 + tid];
    z1[tid] = fmaxf(acc, 0.0f);
  }
  __syncthreads();
  if (tid < 25) {
    float acc = b2[tid];
    for (int c = 0; c < 50; ++c) acc += z1[c] * W2[c * 25 + tid];
    z2[tid] = fmaxf(acc, 0.0f);
  }
  __syncthreads();
  if (tid == 0) {
    float acc = b3[0];
    for (int c = 0; c < 25; ++c) acc += z2[c] * W3[c];
    out[g] = acc;
  }
}

// ---------------- launch ----------------
extern "C" void kernel_launch(void* const* d_in, const int* in_sizes, int n_in,
                              void* d_out, int out_size, void* d_ws, size_t ws_size,
                              hipStream_t stream) {
  const int* x = (const int*)d_in[0];
  const int* ei = (const int*)d_in[1];
  const int* eattr = (const int*)d_in[2];
  const int* batch = (const int*)d_in[3];
  const float* node_emb = (const float*)d_in[4];
  const float* edge_emb = (const float*)d_in[5];
  const float* We = (const float*)d_in[6];
  const float* be = (const float*)d_in[7];
  const float* Wpre = (const float*)d_in[8];
  const float* bpre = (const float*)d_in[9];
  const float* Wpost = (const float*)d_in[10];
  const float* bpost = (const float*)d_in[11];
  const float* Wlin = (const float*)d_in[12];
  const float* blin = (const float*)d_in[13];
  const float* gamma = (const float*)d_in[14];
  const float* beta = (const float*)d_in[15];
  const float* W1 = (const float*)d_in[16];
  const float* b1 = (const float*)d_in[17];
  const float* W2 = (const float*)d_in[18];
  const float* b2 = (const float*)d_in[19];
  const float* W3 = (const float*)d_in[20];
  const float* b3 = (const float*)d_in[21];
  float* out = (float*)d_out;

  const int* src = ei;
  const int* dst = ei + NE;

  char* p = (char*)d_ws;
  auto alloc = [&](size_t bytes) { char* r = p; p += (bytes + 255) & ~(size_t)255; return r; };
  int* deg     = (int*)alloc((size_t)NN * 4);
  int* off     = (int*)alloc((size_t)(NN + 1) * 4);
  int* cursor  = (int*)alloc((size_t)NN * 4);
  int* csrc    = (int*)alloc((size_t)NE * 4);
  int* cattr   = (int*)alloc((size_t)NE * 4);
  float* amp    = (float*)alloc((size_t)NN * 4);
  float* invamp = (float*)alloc((size_t)NN * 4);
  float* hA   = (float*)alloc((size_t)NN * DD * 4);
  float* hB   = (float*)alloc((size_t)NN * DD * 4);
  float* Hsrc = (float*)alloc((size_t)NN * 375 * 4);
  float* Cdst = (float*)alloc((size_t)NN * 375 * 4);
  float* B1    = (float*)alloc((size_t)4 * 75 * 750 * 4);
  float* bias1 = (float*)alloc((size_t)4 * 750 * 4);
  float* WX    = (float*)alloc((size_t)4 * 75 * 75 * 4);
  float* WA    = (float*)alloc((size_t)4 * 3 * 300 * 75 * 4);
  float* etab  = (float*)alloc((size_t)4 * 4 * 375 * 4);
  float* bnpart = (float*)alloc((size_t)BN_BLOCKS * 150 * 4);
  float* musig  = (float*)alloc((size_t)150 * 4);

  hipMemsetAsync(deg, 0, (size_t)NN * 4, stream);
  k_deg<<<(NE + 255) / 256, 256, 0, stream>>>(dst, deg);
  k_scan<<<1, 1024, 0, stream>>>(deg, off);
  k_amp<<<(NN + 255) / 256, 256, 0, stream>>>(deg, off, amp, invamp, cursor);
  k_fill<<<(NE + 255) / 256, 256, 0, stream>>>(src, dst, eattr, cursor, csrc, cattr);
  k_embed<<<(NN * DD + 255) / 256, 256, 0, stream>>>(x, node_emb, hA);
  k_prepack<<<(520500 + 255) / 256, 256, 0, stream>>>(Wpre, bpre, Wpost, B1, bias1, WX, WA);
  k_etab<<<16, 256, 0, stream>>>(edge_emb, We, be, Wpre, etab);

  dim3 g1((750 + 63) / 64, (NN + 63) / 64);
  for (int l = 0; l < NL; ++l) {
    k_gemm1<<<g1, 256, 0, stream>>>(hA, B1 + (size_t)l * 75 * 750, bias1 + l * 750, Hsrc, Cdst);
    k_aggpost<<<NN / NT, 256, 0, stream>>>(hA, Hsrc, Cdst, off, csrc, cattr,
                                           etab + (size_t)l * 4 * 375,
                                           WX + (size_t)l * 75 * 75,
                                           WA + (size_t)l * 3 * 300 * 75,
                                           bpost + l * 75,
                                           Wlin + (size_t)l * 75 * 75,
                                           blin + l * 75,
                                           amp, invamp, hB);
    k_bnstats<<<BN_BLOCKS, 256, 0, stream>>>(hB, bnpart);
    k_bnfinal<<<1, 128, 0, stream>>>(bnpart, musig);
    k_bnapply<<<(NN * DD + 255) / 256, 256, 0, stream>>>(hB, musig, gamma + l * 75, beta + l * 75, hA);
  }
  k_pool_mlp<<<NG, 128, 0, stream>>>(hA, batch, W1, b1, W2, b2, W3, b3, out);
}

// Round 2
// 1503.661 us; speedup vs baseline: 2.9798x; 2.9798x over previous
//
#include <hip/hip_runtime.h>
#include <math.h>

// ---------------- problem constants ----------------
#define NN 50000      // nodes
#define NE 150000     // edges
#define NG 2000       // graphs
#define NL 4          // layers
#define AVG_DEG_LOG 1.1308269950720915f

typedef __attribute__((ext_vector_type(8))) short bf8_t;
typedef __attribute__((ext_vector_type(4))) float f4_t;

__device__ inline unsigned short f2bf(float x) {
  union { float f; unsigned int u; } v; v.f = x;
  unsigned int r = (v.u + 0x7FFFu + ((v.u >> 16) & 1u)) >> 16;
  return (unsigned short)r;
}
__device__ inline float bflo(unsigned int u) { union { unsigned int u; float f; } v; v.u = u << 16; return v.f; }
__device__ inline float bfhi(unsigned int u) { union { unsigned int u; float f; } v; v.u = u & 0xFFFF0000u; return v.f; }

// ---------------- preprocessing ----------------
__global__ void k_deg(const int* __restrict__ dst, int* __restrict__ deg) {
  int e = blockIdx.x * 256 + threadIdx.x;
  if (e < NE) atomicAdd(&deg[dst[e]], 1);
}

__global__ __launch_bounds__(1024) void k_scan(const int* __restrict__ deg, int* __restrict__ off) {
  __shared__ int wsum[16];
  __shared__ int wpre[16];
  __shared__ int carry_s;
  int tid = threadIdx.x, lane = tid & 63, wv = tid >> 6;
  if (tid == 0) carry_s = 0;
  __syncthreads();
  for (int base = 0; base < NN; base += 1024) {
    int i = base + tid;
    int v = (i < NN) ? deg[i] : 0;
    int incl = v;
    #pragma unroll
    for (int d = 1; d < 64; d <<= 1) { int t = __shfl_up(incl, d); if (lane >= d) incl += t; }
    if (lane == 63) wsum[wv] = incl;
    __syncthreads();
    if (wv == 0) {
      int s = (lane < 16) ? wsum[lane] : 0;
      int sc = s;
      #pragma unroll
      for (int d = 1; d < 16; d <<= 1) { int t = __shfl_up(sc, d); if (lane >= d) sc += t; }
      if (lane < 16) wpre[lane] = sc - s;
    }
    __syncthreads();
    int carry = carry_s;
    int excl = carry + wpre[wv] + incl - v;
    if (i < NN) off[i] = excl;
    __syncthreads();
    if (tid == 1023) carry_s = excl + v;
    __syncthreads();
  }
  if (tid == 0) off[NN] = carry_s;
}

__global__ void k_amp(const int* __restrict__ deg, const int* __restrict__ off,
                      float* __restrict__ amp, float* __restrict__ invamp, int* __restrict__ cursor) {
  int n = blockIdx.x * 256 + threadIdx.x;
  if (n < NN) {
    int d = deg[n]; if (d < 1) d = 1;
    float a = logf((float)d + 1.0f) / AVG_DEG_LOG;
    amp[n] = a; invamp[n] = 1.0f / a;
    cursor[n] = off[n];
  }
}

__global__ void k_fill(const int* __restrict__ src, const int* __restrict__ dst,
                       const int* __restrict__ attr, int* __restrict__ cursor,
                       int* __restrict__ csrc, int* __restrict__ cattr) {
  int e = blockIdx.x * 256 + threadIdx.x;
  if (e < NE) {
    int d = dst[e];
    int p = atomicAdd(&cursor[d], 1);
    csrc[p] = src[e];
    cattr[p] = attr[e];
  }
}

// node embedding -> hbf [NN,96] bf16 (cols 75..95 zero)
__global__ void k_embed(const int* __restrict__ x, const float* __restrict__ emb, unsigned short* __restrict__ hbf) {
  int i = blockIdx.x * 256 + threadIdx.x;
  if (i < NN * 96) {
    int n = i / 96, c = i - (i / 96) * 96;
    hbf[i] = (c < 75) ? f2bf(emb[x[n] * 75 + c]) : (unsigned short)0;
  }
}

// ---------------- weight prep ----------------
// WXlin[l][k][j] = sum_o Wpost_x[l][k][o] * Wlin[l][o][j]   (f32, 4*75*75)
__global__ void k_wxlin(const float* __restrict__ Wpost, const float* __restrict__ Wlin, float* __restrict__ WXlin) {
  int l = blockIdx.x;
  for (int idx = threadIdx.x; idx < 5625; idx += 256) {
    int k = idx / 75, j = idx - (idx / 75) * 75;
    float s = 0.0f;
    for (int o = 0; o < 75; ++o) {
      int t = o / 15, jj = o - t * 15;
      s += Wpost[((l * 5 + t) * 975 + k) * 15 + jj] * Wlin[l * 5625 + o * 75 + j];
    }
    WXlin[l * 5625 + idx] = s;
  }
}

// zb[l][j] = blin[l][j] + sum_o bpost[l][o]*Wlin[l][o][j]
__global__ void k_zb(const float* __restrict__ bpost, const float* __restrict__ blin,
                     const float* __restrict__ Wlin, float* __restrict__ zb) {
  int l = blockIdx.x, j = threadIdx.x;
  if (j < 75) {
    float s = blin[l * 75 + j];
    for (int o = 0; o < 75; ++o) s += bpost[l * 75 + o] * Wlin[l * 5625 + o * 75 + j];
    zb[l * 75 + j] = s;
  }
}

// B1T bf16 [4][896][96]:  col c<375: src block; 384<=c<759: dst block; 759<=c<834: WXlin; else 0
__global__ void k_packB1(const float* __restrict__ Wpre, const float* __restrict__ WXlin,
                         unsigned short* __restrict__ B1T) {
  int idx = blockIdx.x * 256 + threadIdx.x;
  if (idx >= 4 * 896 * 96) return;
  int l = idx / (896 * 96); int rem = idx - l * (896 * 96);
  int c = rem / 96, k = rem - (rem / 96) * 96;
  float v = 0.0f;
  if (k < 75) {
    if (c < 375) {
      int t = c / 75, f = c - t * 75;
      v = Wpre[((l * 5 + t) * 225 + 75 + k) * 75 + f];
    } else if (c >= 384 && c < 759) {
      int o = c - 384; int t = o / 75, f = o - t * 75;
      v = Wpre[((l * 5 + t) * 225 + k) * 75 + f];
    } else if (c >= 759 && c < 834) {
      v = WXlin[l * 5625 + k * 75 + (c - 759)];
    }
  }
  B1T[idx] = f2bf(v);
}

// WcombT bf16 [4][5][48][320]: [j][k] with j=s*15+jj (45 real), k=agg*75+f (300 real)
__global__ void k_packWcomb(const float* __restrict__ Wpost, unsigned short* __restrict__ WcombT) {
  int idx = blockIdx.x * 256 + threadIdx.x;
  if (idx >= 4 * 5 * 48 * 320) return;
  int l = idx / (5 * 48 * 320); int rem = idx - l * (5 * 48 * 320);
  int t = rem / (48 * 320); rem -= t * (48 * 320);
  int j = rem / 320, k = rem - (rem / 320) * 320;
  float v = 0.0f;
  if (j < 45 && k < 300) {
    int s = j / 15, jj = j - s * 15;
    v = Wpost[((l * 5 + t) * 975 + 75 + s * 300 + k) * 15 + jj];
  }
  WcombT[idx] = f2bf(v);
}

// WlinT bf16 [4][80][96]
__global__ void k_packWlin(const float* __restrict__ Wlin, unsigned short* __restrict__ WlinT) {
  int idx = blockIdx.x * 256 + threadIdx.x;
  if (idx >= 4 * 80 * 96) return;
  int l = idx / (80 * 96); int rem = idx - l * (80 * 96);
  int j = rem / 96, k = rem - (rem / 96) * 96;
  float v = (j < 75 && k < 75) ? Wlin[l * 5625 + k * 75 + j] : 0.0f;
  WlinT[idx] = f2bf(v);
}

// etab f32 [4][4][384]: (edge_emb[a]@We[l]+be[l]) @ Wpre_e-block, zero-padded to 384
__global__ void k_etab(const float* __restrict__ edge_emb, const float* __restrict__ We,
                       const float* __restrict__ be, const float* __restrict__ Wpre,
                       float* __restrict__ etab) {
  __shared__ float ev[75];
  int l = blockIdx.x >> 2, a = blockIdx.x & 3;
  int tid = threadIdx.x;
  if (tid < 75) {
    float acc = be[l * 75 + tid];
    for (int k = 0; k < 50; ++k) acc += edge_emb[a * 50 + k] * We[(l * 50 + k) * 75 + tid];
    ev[tid] = acc;
  }
  __syncthreads();
  for (int tf = tid; tf < 384; tf += 256) {
    float acc = 0.0f;
    if (tf < 375) {
      int t = tf / 75, f = tf - t * 75;
      for (int d = 0; d < 75; ++d) acc += ev[d] * Wpre[((l * 5 + t) * 225 + 150 + d) * 75 + f];
    }
    etab[(l * 4 + a) * 384 + tf] = acc;
  }
}

// ---------------- GEMM1 (MFMA): [NN,96]bf16 @ [96,896]bf16 -> Hsrc bf16 / Cdst f32(+bpre) / Xpart f32
__global__ __launch_bounds__(256) void k_gemm1(const unsigned short* __restrict__ hbf,
                                               const unsigned short* __restrict__ B1T_l,
                                               const float* __restrict__ bpre_l,
                                               unsigned short* __restrict__ Hsrc,
                                               float* __restrict__ Cdst,
                                               float* __restrict__ Xpart) {
  int w = threadIdx.x >> 6, lane = threadIdx.x & 63;
  int l15 = lane & 15, l4 = lane >> 4;
  int m0 = blockIdx.y * 64 + w * 16;
  int n0 = blockIdx.x * 128;
  int mA = m0 + l15; if (mA >= NN) mA = NN - 1;
  bf8_t a0 = *(const bf8_t*)(hbf + (size_t)mA * 96 + l4 * 8);
  bf8_t a1 = *(const bf8_t*)(hbf + (size_t)mA * 96 + 32 + l4 * 8);
  bf8_t a2 = *(const bf8_t*)(hbf + (size_t)mA * 96 + 64 + l4 * 8);
  #pragma unroll
  for (int nf = 0; nf < 8; ++nf) {
    int c = n0 + nf * 16 + l15;
    const unsigned short* bp = B1T_l + (size_t)c * 96 + l4 * 8;
    f4_t acc = {0.f, 0.f, 0.f, 0.f};
    acc = __builtin_amdgcn_mfma_f32_16x16x32_bf16(a0, *(const bf8_t*)(bp), acc, 0, 0, 0);
    acc = __builtin_amdgcn_mfma_f32_16x16x32_bf16(a1, *(const bf8_t*)(bp + 32), acc, 0, 0, 0);
    acc = __builtin_amdgcn_mfma_f32_16x16x32_bf16(a2, *(const bf8_t*)(bp + 64), acc, 0, 0, 0);
    #pragma unroll
    for (int i = 0; i < 4; ++i) {
      int m = m0 + l4 * 4 + i;
      if (m < NN) {
        if (c < 384) Hsrc[(size_t)m * 384 + c] = f2bf(acc[i]);
        else if (c < 759) Cdst[(size_t)m * 375 + (c - 384)] = acc[i] + bpre_l[c - 384];
        else if (c < 834) Xpart[(size_t)m * 75 + (c - 759)] = acc[i];
      }
    }
  }
}

// ---------------- fused aggregation (registers) + per-tower MFMA post + scaler combine ----------------
__global__ __launch_bounds__(256) void k_agg(const unsigned short* __restrict__ Hsrc,
                                             const float* __restrict__ Cdst,
                                             const int* __restrict__ off,
                                             const int* __restrict__ csrc,
                                             const int* __restrict__ cattr,
                                             const float* __restrict__ etab_l,
                                             const unsigned short* __restrict__ WcombT_l,
                                             const float* __restrict__ amp,
                                             const float* __restrict__ invamp,
                                             unsigned short* __restrict__ Cbf) {
  __shared__ unsigned short A_s[16 * 1608];   // [16 nodes][5 towers * 320 + pad8] bf16
  __shared__ float Out_s[16 * 256];           // [16 nodes][5 towers * 48 +pad]
  __shared__ float et_s[4 * 384];
  int tid = threadIdx.x;
  int w = tid >> 6, lane = tid & 63;
  int l15 = lane & 15, l4 = lane >> 4;
  int n0 = blockIdx.x * 16;

  // zero A (incl. K-pads), stage etab
  {
    unsigned int* A32 = (unsigned int*)A_s;
    for (int i = tid; i < 16 * 1608 / 2; i += 256) A32[i] = 0u;
    for (int i = tid; i < 4 * 384; i += 256) et_s[i] = etab_l[i];
  }
  __syncthreads();

  // each wave: 4 nodes, register accumulation over CSR edges
  int c0 = lane * 6;
  for (int r = 0; r < 4; ++r) {
    int nl = w * 4 + r;
    int g = n0 + nl;            // NN divisible by 16 -> always valid
    int e0 = off[g], e1 = off[g + 1];
    float s6[6] = {0,0,0,0,0,0}, q6[6] = {0,0,0,0,0,0};
    float mn6[6], mx6[6];
    #pragma unroll
    for (int i = 0; i < 6; ++i) { mn6[i] = 3.402823466e+38f; mx6[i] = -3.402823466e+38f; }
    for (int e = e0; e < e1; ++e) {
      int sidx = csrc[e];
      int a = cattr[e];
      const unsigned int* hp = (const unsigned int*)(Hsrc + (size_t)sidx * 384);
      unsigned int u0 = hp[lane * 3], u1 = hp[lane * 3 + 1], u2 = hp[lane * 3 + 2];
      float v[6] = { bflo(u0), bfhi(u0), bflo(u1), bfhi(u1), bflo(u2), bfhi(u2) };
      const float* ep = et_s + a * 384 + c0;
      #pragma unroll
      for (int i = 0; i < 6; ++i) {
        float q = v[i] + ep[i];
        s6[i] += q;
        q6[i] = fmaf(q, q, q6[i]);
        mn6[i] = fminf(mn6[i], q);
        mx6[i] = fmaxf(mx6[i], q);
      }
    }
    int d = e1 - e0;
    float inv = (d > 0) ? (1.0f / (float)d) : 0.0f;
    #pragma unroll
    for (int i = 0; i < 6; ++i) {
      int c = c0 + i;
      if (c < 375) {
        float mean, mnv, mxv, sd;
        if (d > 0) {
          float cd = Cdst[(size_t)g * 375 + c];
          float mu = s6[i] * inv;
          mean = cd + mu;
          mnv = cd + mn6[i];
          mxv = cd + mx6[i];
          sd = sqrtf(fmaxf(q6[i] * inv - mu * mu, 0.0f) + 1e-5f);
        } else {
          mean = 0.0f; mnv = 0.0f; mxv = 0.0f; sd = 0.0031622776601683794f;
        }
        int t = c / 75, f = c - t * 75;
        unsigned short* Ab = A_s + nl * 1608 + t * 320;
        Ab[f] = f2bf(mean);
        Ab[75 + f] = f2bf(mnv);
        Ab[150 + f] = f2bf(mxv);
        Ab[225 + f] = f2bf(sd);
      }
    }
  }
  __syncthreads();

  // MFMA: per (tower t, nfrag nf): [16 nodes x 320k] @ [320k x 16j]
  for (int task = w; task < 15; task += 4) {
    int t = task % 5, nf = task / 5;
    f4_t acc = {0.f, 0.f, 0.f, 0.f};
    const unsigned short* wp = WcombT_l + (size_t)(t * 48 + nf * 16 + l15) * 320 + l4 * 8;
    const unsigned short* ap = A_s + l15 * 1608 + t * 320 + l4 * 8;
    #pragma unroll
    for (int ks = 0; ks < 10; ++ks) {
      bf8_t av = *(const bf8_t*)(ap + ks * 32);
      bf8_t bv = *(const bf8_t*)(wp + ks * 32);
      acc = __builtin_amdgcn_mfma_f32_16x16x32_bf16(av, bv, acc, 0, 0, 0);
    }
    int colb = t * 48 + nf * 16 + l15;
    #pragma unroll
    for (int i = 0; i < 4; ++i) Out_s[(l4 * 4 + i) * 256 + colb] = acc[i];
  }
  __syncthreads();

  // combine scalers -> Cbf [NN,96] bf16 (pad cols zero)
  for (int item = tid; item < 16 * 96; item += 256) {
    int n = item / 96, o = item - (item / 96) * 96;
    int g = n0 + n;
    unsigned short v = 0;
    if (o < 75) {
      int t = o / 15, jj = o - t * 15;
      const float* ob = Out_s + n * 256 + t * 48;
      float cval = ob[jj] + amp[g] * ob[15 + jj] + invamp[g] * ob[30 + jj];
      v = f2bf(cval);
    }
    Cbf[(size_t)g * 96 + o] = v;
  }
}

// ---------------- GEMM2 (MFMA): Z = Cbf@Wlin + Xpart + zb ----------------
__global__ __launch_bounds__(256) void k_gemm2(const unsigned short* __restrict__ Cbf,
                                               const unsigned short* __restrict__ WlinT_l,
                                               const float* __restrict__ Xpart,
                                               const float* __restrict__ zb_l,
                                               float* __restrict__ Z) {
  int w = threadIdx.x >> 6, lane = threadIdx.x & 63;
  int l15 = lane & 15, l4 = lane >> 4;
  int m0 = blockIdx.x * 64 + w * 16;
  int mA = m0 + l15; if (mA >= NN) mA = NN - 1;
  bf8_t a0 = *(const bf8_t*)(Cbf + (size_t)mA * 96 + l4 * 8);
  bf8_t a1 = *(const bf8_t*)(Cbf + (size_t)mA * 96 + 32 + l4 * 8);
  bf8_t a2 = *(const bf8_t*)(Cbf + (size_t)mA * 96 + 64 + l4 * 8);
  #pragma unroll
  for (int nf = 0; nf < 5; ++nf) {
    int c = nf * 16 + l15;
    const unsigned short* bp = WlinT_l + (size_t)c * 96 + l4 * 8;
    f4_t acc = {0.f, 0.f, 0.f, 0.f};
    acc = __builtin_amdgcn_mfma_f32_16x16x32_bf16(a0, *(const bf8_t*)(bp), acc, 0, 0, 0);
    acc = __builtin_amdgcn_mfma_f32_16x16x32_bf16(a1, *(const bf8_t*)(bp + 32), acc, 0, 0, 0);
    acc = __builtin_amdgcn_mfma_f32_16x16x32_bf16(a2, *(const bf8_t*)(bp + 64), acc, 0, 0, 0);
    if (c < 75) {
      #pragma unroll
      for (int i = 0; i < 4; ++i) {
        int m = m0 + l4 * 4 + i;
        if (m < NN) Z[(size_t)m * 75 + c] = acc[i] + Xpart[(size_t)m * 75 + c] + zb_l[c];
      }
    }
  }
}

// ---------------- batchnorm ----------------
#define BN_BLOCKS 96
#define BN_ROWS 521
__global__ __launch_bounds__(256) void k_bnstats(const float* __restrict__ Z, float* __restrict__ partial) {
  __shared__ float sArr[225];
  __shared__ float qArr[225];
  int tid = threadIdx.x;
  int r0 = blockIdx.x * BN_ROWS;
  int r1 = r0 + BN_ROWS; if (r1 > NN) r1 = NN;
  float s = 0.0f, q = 0.0f;
  if (tid < 225) {
    int rr = tid / 75, c = tid - rr * 75;
    for (int r = r0 + rr; r < r1; r += 3) {
      float v = Z[(size_t)r * 75 + c];
      s += v; q += v * v;
    }
    sArr[tid] = s; qArr[tid] = q;
  }
  __syncthreads();
  if (tid < 75) {
    float S = sArr[tid] + sArr[75 + tid] + sArr[150 + tid];
    float Q = qArr[tid] + qArr[75 + tid] + qArr[150 + tid];
    partial[blockIdx.x * 150 + tid] = S;
    partial[blockIdx.x * 150 + 75 + tid] = Q;
  }
}

__global__ void k_bnfinal(const float* __restrict__ partial, float* __restrict__ musig) {
  int c = threadIdx.x;
  if (c < 75) {
    float S = 0.0f, Q = 0.0f;
    for (int b = 0; b < BN_BLOCKS; ++b) { S += partial[b * 150 + c]; Q += partial[b * 150 + 75 + c]; }
    float mu = S * (1.0f / NN);
    float var = fmaxf(Q * (1.0f / NN) - mu * mu, 0.0f);
    musig[c] = mu;
    musig[75 + c] = 1.0f / sqrtf(var + 1e-5f);
  }
}

// BN apply + relu -> hbf bf16 [NN,96] and hf32 [NN,75]
__global__ void k_bnapply(const float* __restrict__ Z, const float* __restrict__ musig,
                          const float* __restrict__ gamma_l, const float* __restrict__ beta_l,
                          unsigned short* __restrict__ hbf, float* __restrict__ hf32) {
  int i = blockIdx.x * 256 + threadIdx.x;
  if (i < NN * 96) {
    int n = i / 96, c = i - (i / 96) * 96;
    if (c < 75) {
      float v = (Z[(size_t)n * 75 + c] - musig[c]) * musig[75 + c];
      v = fmaxf(gamma_l[c] * v + beta_l[c], 0.0f);
      hbf[i] = f2bf(v);
      hf32[(size_t)n * 75 + c] = v;
    } else {
      hbf[i] = 0;
    }
  }
}

// ---------------- pool + MLP head ----------------
__global__ __launch_bounds__(128) void k_pool_mlp(const float* __restrict__ h, const int* __restrict__ batch,
                                                  const float* __restrict__ W1, const float* __restrict__ b1,
                                                  const float* __restrict__ W2, const float* __restrict__ b2,
                                                  const float* __restrict__ W3, const float* __restrict__ b3,
                                                  float* __restrict__ out) {
  __shared__ float pooled[75];
  __shared__ float z1[50];
  __shared__ float z2[25];
  __shared__ int se[2];
  int g = blockIdx.x, tid = threadIdx.x;
  if (tid < 2) {
    int target = g + tid;
    int lo = 0, hi = NN;
    while (lo < hi) { int mid = (lo + hi) >> 1; if (batch[mid] < target) lo = mid + 1; else hi = mid; }
    se[tid] = lo;
  }
  __syncthreads();
  int s = se[0], e = se[1];
  if (tid < 75) {
    float acc = 0.0f;
    for (int r = s; r < e; ++r) acc += h[(size_t)r * 75 + tid];
    pooled[tid] = acc;
  }
  __syncthreads();
  if (tid < 50) {
    float acc = b1[tid];
    for (int c = 0; c < 75; ++c) acc += pooled[c] * W1[c * 50 + tid];
    z1[tid] = fmaxf(acc, 0.0f);
  }
  __syncthreads();
  if (tid < 25) {
    float acc = b2[tid];
    for (int c = 0; c < 50; ++c) acc += z1[c] * W2[c * 25 + tid];
    z2[tid] = fmaxf(acc, 0.0f);
  }
  __syncthreads();
  if (tid == 0) {
    float acc = b3[0];
    for (int c = 0; c < 25; ++c) acc += z2[c] * W3[c];
    out[g] = acc;
  }
}

// ---------------- launch ----------------
extern "C" void kernel_launch(void* const* d_in, const int* in_sizes, int n_in,
                              void* d_out, int out_size, void* d_ws, size_t ws_size,
                              hipStream_t stream) {
  const int* x = (const int*)d_in[0];
  const int* ei = (const int*)d_in[1];
  const int* eattr = (const int*)d_in[2];
  const int* batch = (const int*)d_in[3];
  const float* node_emb = (const float*)d_in[4];
  const float* edge_emb = (const float*)d_in[5];
  const float* We = (const float*)d_in[6];
  const float* be = (const float*)d_in[7];
  const float* Wpre = (const float*)d_in[8];
  const float* bpre = (const float*)d_in[9];
  const float* Wpost = (const float*)d_in[10];
  const float* bpost = (const float*)d_in[11];
  const float* Wlin = (const float*)d_in[12];
  const float* blin = (const float*)d_in[13];
  const float* gamma = (const float*)d_in[14];
  const float* beta = (const float*)d_in[15];
  const float* W1 = (const float*)d_in[16];
  const float* b1 = (const float*)d_in[17];
  const float* W2 = (const float*)d_in[18];
  const float* b2 = (const float*)d_in[19];
  const float* W3 = (const float*)d_in[20];
  const float* b3 = (const float*)d_in[21];
  float* out = (float*)d_out;

  const int* src = ei;
  const int* dst = ei + NE;

  char* p = (char*)d_ws;
  auto alloc = [&](size_t bytes) { char* r = p; p += (bytes + 255) & ~(size_t)255; return r; };
  int* deg     = (int*)alloc((size_t)NN * 4);
  int* off     = (int*)alloc((size_t)(NN + 1) * 4);
  int* cursor  = (int*)alloc((size_t)NN * 4);
  int* csrc    = (int*)alloc((size_t)NE * 4);
  int* cattr   = (int*)alloc((size_t)NE * 4);
  float* amp    = (float*)alloc((size_t)NN * 4);
  float* invamp = (float*)alloc((size_t)NN * 4);
  unsigned short* hbf  = (unsigned short*)alloc((size_t)NN * 96 * 2);
  float* hf32          = (float*)alloc((size_t)NN * 75 * 4);
  unsigned short* Hsrc = (unsigned short*)alloc((size_t)NN * 384 * 2);
  float* Cdst          = (float*)alloc((size_t)NN * 375 * 4);
  float* Xpart         = (float*)alloc((size_t)NN * 75 * 4);
  unsigned short* Cbf  = (unsigned short*)alloc((size_t)NN * 96 * 2);
  float* Z             = (float*)alloc((size_t)NN * 75 * 4);
  unsigned short* B1T    = (unsigned short*)alloc((size_t)4 * 896 * 96 * 2);
  unsigned short* WcombT = (unsigned short*)alloc((size_t)4 * 5 * 48 * 320 * 2);
  unsigned short* WlinT  = (unsigned short*)alloc((size_t)4 * 80 * 96 * 2);
  float* WXlin = (float*)alloc((size_t)4 * 5625 * 4);
  float* zb    = (float*)alloc((size_t)4 * 75 * 4);
  float* etab  = (float*)alloc((size_t)4 * 4 * 384 * 4);
  float* bnpart = (float*)alloc((size_t)BN_BLOCKS * 150 * 4);
  float* musig  = (float*)alloc((size_t)150 * 4);

  hipMemsetAsync(deg, 0, (size_t)NN * 4, stream);
  k_deg<<<(NE + 255) / 256, 256, 0, stream>>>(dst, deg);
  k_scan<<<1, 1024, 0, stream>>>(deg, off);
  k_amp<<<(NN + 255) / 256, 256, 0, stream>>>(deg, off, amp, invamp, cursor);
  k_fill<<<(NE + 255) / 256, 256, 0, stream>>>(src, dst, eattr, cursor, csrc, cattr);
  k_embed<<<(NN * 96 + 255) / 256, 256, 0, stream>>>(x, node_emb, hbf);
  k_wxlin<<<4, 256, 0, stream>>>(Wpost, Wlin, WXlin);
  k_zb<<<4, 128, 0, stream>>>(bpost, blin, Wlin, zb);
  k_packB1<<<(4 * 896 * 96 + 255) / 256, 256, 0, stream>>>(Wpre, WXlin, B1T);
  k_packWcomb<<<(4 * 5 * 48 * 320 + 255) / 256, 256, 0, stream>>>(Wpost, WcombT);
  k_packWlin<<<(4 * 80 * 96 + 255) / 256, 256, 0, stream>>>(Wlin, WlinT);
  k_etab<<<16, 256, 0, stream>>>(edge_emb, We, be, Wpre, etab);

  dim3 g1(7, (NN + 63) / 64);
  for (int l = 0; l < NL; ++l) {
    k_gemm1<<<g1, 256, 0, stream>>>(hbf, B1T + (size_t)l * 896 * 96, bpre + l * 375, Hsrc, Cdst, Xpart);
    k_agg<<<NN / 16, 256, 0, stream>>>(Hsrc, Cdst, off, csrc, cattr,
                                       etab + (size_t)l * 4 * 384,
                                       WcombT + (size_t)l * 5 * 48 * 320,
                                       amp, invamp, Cbf);
    k_gemm2<<<(NN + 63) / 64, 256, 0, stream>>>(Cbf, WlinT + (size_t)l * 80 * 96, Xpart, zb + l * 75, Z);
    k_bnstats<<<BN_BLOCKS, 256, 0, stream>>>(Z, bnpart);
    k_bnfinal<<<1, 128, 0, stream>>>(bnpart, musig);
    k_bnapply<<<(NN * 96 + 255) / 256, 256, 0, stream>>>(Z, musig, gamma + l * 75, beta + l * 75, hbf, hf32);
  }
  k_pool_mlp<<<NG, 128, 0, stream>>>(hf32, batch, W1, b1, W2, b2, W3, b3, out);
}

// Round 3
// 1324.071 us; speedup vs baseline: 3.3840x; 1.1356x over previous
//
#include <hip/hip_runtime.h>
#include <math.h>

// ---------------- problem constants ----------------
#define NN 50000      // nodes
#define NE 150000     // edges
#define NG 2000       // graphs
#define NL 4          // layers
#define AVG_DEG_LOG 1.1308269950720915f

typedef __attribute__((ext_vector_type(8))) short bf8_t;
typedef __attribute__((ext_vector_type(4))) float f4_t;

__device__ inline unsigned short f2bf(float x) {
  union { float f; unsigned int u; } v; v.f = x;
  unsigned int r = (v.u + 0x7FFFu + ((v.u >> 16) & 1u)) >> 16;
  return (unsigned short)r;
}
__device__ inline float bflo(unsigned int u) { union { unsigned int u; float f; } v; v.u = u << 16; return v.f; }
__device__ inline float bfhi(unsigned int u) { union { unsigned int u; float f; } v; v.u = u & 0xFFFF0000u; return v.f; }

// ---------------- preprocessing ----------------
__global__ void k_deg(const int* __restrict__ dst, int* __restrict__ deg) {
  int e = blockIdx.x * 256 + threadIdx.x;
  if (e < NE) atomicAdd(&deg[dst[e]], 1);
}

__global__ __launch_bounds__(1024) void k_scan(const int* __restrict__ deg, int* __restrict__ off) {
  __shared__ int wsum[16];
  __shared__ int wpre[16];
  __shared__ int carry_s;
  int tid = threadIdx.x, lane = tid & 63, wv = tid >> 6;
  if (tid == 0) carry_s = 0;
  __syncthreads();
  for (int base = 0; base < NN; base += 1024) {
    int i = base + tid;
    int v = (i < NN) ? deg[i] : 0;
    int incl = v;
    #pragma unroll
    for (int d = 1; d < 64; d <<= 1) { int t = __shfl_up(incl, d); if (lane >= d) incl += t; }
    if (lane == 63) wsum[wv] = incl;
    __syncthreads();
    if (wv == 0) {
      int s = (lane < 16) ? wsum[lane] : 0;
      int sc = s;
      #pragma unroll
      for (int d = 1; d < 16; d <<= 1) { int t = __shfl_up(sc, d); if (lane >= d) sc += t; }
      if (lane < 16) wpre[lane] = sc - s;
    }
    __syncthreads();
    int carry = carry_s;
    int excl = carry + wpre[wv] + incl - v;
    if (i < NN) off[i] = excl;
    __syncthreads();
    if (tid == 1023) carry_s = excl + v;
    __syncthreads();
  }
  if (tid == 0) off[NN] = carry_s;
}

__global__ void k_amp(const int* __restrict__ deg, const int* __restrict__ off,
                      float* __restrict__ amp, float* __restrict__ invamp, int* __restrict__ cursor) {
  int n = blockIdx.x * 256 + threadIdx.x;
  if (n < NN) {
    int d = deg[n]; if (d < 1) d = 1;
    float a = logf((float)d + 1.0f) / AVG_DEG_LOG;
    amp[n] = a; invamp[n] = 1.0f / a;
    cursor[n] = off[n];
  }
}

// pack src (16 bit) | attr (<<16) into one u32 per CSR slot
__global__ void k_fill(const int* __restrict__ src, const int* __restrict__ dst,
                       const int* __restrict__ attr, int* __restrict__ cursor,
                       unsigned int* __restrict__ cpack) {
  int e = blockIdx.x * 256 + threadIdx.x;
  if (e < NE) {
    int d = dst[e];
    int p = atomicAdd(&cursor[d], 1);
    cpack[p] = (unsigned int)src[e] | ((unsigned int)attr[e] << 16);
  }
}

// node embedding -> hbf [NN,96] bf16 (cols 75..95 zero)
__global__ void k_embed(const int* __restrict__ x, const float* __restrict__ emb, unsigned short* __restrict__ hbf) {
  int i = blockIdx.x * 256 + threadIdx.x;
  if (i < NN * 96) {
    int n = i / 96, c = i - (i / 96) * 96;
    hbf[i] = (c < 75) ? f2bf(emb[x[n] * 75 + c]) : (unsigned short)0;
  }
}

// ---------------- weight prep ----------------
__global__ void k_wxlin(const float* __restrict__ Wpost, const float* __restrict__ Wlin, float* __restrict__ WXlin) {
  int l = blockIdx.x;
  for (int idx = threadIdx.x; idx < 5625; idx += 256) {
    int k = idx / 75, j = idx - (idx / 75) * 75;
    float s = 0.0f;
    for (int o = 0; o < 75; ++o) {
      int t = o / 15, jj = o - t * 15;
      s += Wpost[((l * 5 + t) * 975 + k) * 15 + jj] * Wlin[l * 5625 + o * 75 + j];
    }
    WXlin[l * 5625 + idx] = s;
  }
}

__global__ void k_zb(const float* __restrict__ bpost, const float* __restrict__ blin,
                     const float* __restrict__ Wlin, float* __restrict__ zb) {
  int l = blockIdx.x, j = threadIdx.x;
  if (j < 75) {
    float s = blin[l * 75 + j];
    for (int o = 0; o < 75; ++o) s += bpost[l * 75 + o] * Wlin[l * 5625 + o * 75 + j];
    zb[l * 75 + j] = s;
  }
}

// B1T bf16 [4][896][96]:  col c<375: src block; 384<=c<759: dst block; 759<=c<834: WXlin; else 0
__global__ void k_packB1(const float* __restrict__ Wpre, const float* __restrict__ WXlin,
                         unsigned short* __restrict__ B1T) {
  int idx = blockIdx.x * 256 + threadIdx.x;
  if (idx >= 4 * 896 * 96) return;
  int l = idx / (896 * 96); int rem = idx - l * (896 * 96);
  int c = rem / 96, k = rem - (rem / 96) * 96;
  float v = 0.0f;
  if (k < 75) {
    if (c < 375) {
      int t = c / 75, f = c - t * 75;
      v = Wpre[((l * 5 + t) * 225 + 75 + k) * 75 + f];
    } else if (c >= 384 && c < 759) {
      int o = c - 384; int t = o / 75, f = o - t * 75;
      v = Wpre[((l * 5 + t) * 225 + k) * 75 + f];
    } else if (c >= 759 && c < 834) {
      v = WXlin[l * 5625 + k * 75 + (c - 759)];
    }
  }
  B1T[idx] = f2bf(v);
}

// WcombT bf16 [4][5][48][320]: row j=s*15+jj (45 real), col k INTERLEAVED: k = f*4 + agg  (k<300 real)
__global__ void k_packWcomb(const float* __restrict__ Wpost, unsigned short* __restrict__ WcombT) {
  int idx = blockIdx.x * 256 + threadIdx.x;
  if (idx >= 4 * 5 * 48 * 320) return;
  int l = idx / (5 * 48 * 320); int rem = idx - l * (5 * 48 * 320);
  int t = rem / (48 * 320); rem -= t * (48 * 320);
  int j = rem / 320, k = rem - (rem / 320) * 320;
  float v = 0.0f;
  if (j < 45 && k < 300) {
    int s = j / 15, jj = j - s * 15;
    int f = k >> 2, agg = k & 3;
    v = Wpost[((l * 5 + t) * 975 + 75 + s * 300 + agg * 75 + f) * 15 + jj];
  }
  WcombT[idx] = f2bf(v);
}

// WlinT bf16 [4][80][96]: row j (output col), k = post_nn index
__global__ void k_packWlin(const float* __restrict__ Wlin, unsigned short* __restrict__ WlinT) {
  int idx = blockIdx.x * 256 + threadIdx.x;
  if (idx >= 4 * 80 * 96) return;
  int l = idx / (80 * 96); int rem = idx - l * (80 * 96);
  int j = rem / 96, k = rem - (rem / 96) * 96;
  float v = (j < 75 && k < 75) ? Wlin[l * 5625 + k * 75 + j] : 0.0f;
  WlinT[idx] = f2bf(v);
}

// etab f32 [4][4][384]
__global__ void k_etab(const float* __restrict__ edge_emb, const float* __restrict__ We,
                       const float* __restrict__ be, const float* __restrict__ Wpre,
                       float* __restrict__ etab) {
  __shared__ float ev[75];
  int l = blockIdx.x >> 2, a = blockIdx.x & 3;
  int tid = threadIdx.x;
  if (tid < 75) {
    float acc = be[l * 75 + tid];
    for (int k = 0; k < 50; ++k) acc += edge_emb[a * 50 + k] * We[(l * 50 + k) * 75 + tid];
    ev[tid] = acc;
  }
  __syncthreads();
  for (int tf = tid; tf < 384; tf += 256) {
    float acc = 0.0f;
    if (tf < 375) {
      int t = tf / 75, f = tf - t * 75;
      for (int d = 0; d < 75; ++d) acc += ev[d] * Wpre[((l * 5 + t) * 225 + 150 + d) * 75 + f];
    }
    etab[(l * 4 + a) * 384 + tf] = acc;
  }
}

// ---------------- GEMM1 (MFMA): [NN,96]bf16 @ [96,896]bf16 -> Hsrc bf16 / Cdst f32(+bpre) / Xpart f32
__global__ __launch_bounds__(256) void k_gemm1(const unsigned short* __restrict__ hbf,
                                               const unsigned short* __restrict__ B1T_l,
                                               const float* __restrict__ bpre_l,
                                               unsigned short* __restrict__ Hsrc,
                                               float* __restrict__ Cdst,
                                               float* __restrict__ Xpart) {
  int w = threadIdx.x >> 6, lane = threadIdx.x & 63;
  int l15 = lane & 15, l4 = lane >> 4;
  int m0 = blockIdx.y * 64 + w * 16;
  int n0 = blockIdx.x * 128;
  int mA = m0 + l15; if (mA >= NN) mA = NN - 1;
  bf8_t a0 = *(const bf8_t*)(hbf + (size_t)mA * 96 + l4 * 8);
  bf8_t a1 = *(const bf8_t*)(hbf + (size_t)mA * 96 + 32 + l4 * 8);
  bf8_t a2 = *(const bf8_t*)(hbf + (size_t)mA * 96 + 64 + l4 * 8);
  #pragma unroll
  for (int nf = 0; nf < 8; ++nf) {
    int c = n0 + nf * 16 + l15;
    const unsigned short* bp = B1T_l + (size_t)c * 96 + l4 * 8;
    f4_t acc = {0.f, 0.f, 0.f, 0.f};
    acc = __builtin_amdgcn_mfma_f32_16x16x32_bf16(a0, *(const bf8_t*)(bp), acc, 0, 0, 0);
    acc = __builtin_amdgcn_mfma_f32_16x16x32_bf16(a1, *(const bf8_t*)(bp + 32), acc, 0, 0, 0);
    acc = __builtin_amdgcn_mfma_f32_16x16x32_bf16(a2, *(const bf8_t*)(bp + 64), acc, 0, 0, 0);
    #pragma unroll
    for (int i = 0; i < 4; ++i) {
      int m = m0 + l4 * 4 + i;
      if (m < NN) {
        if (c < 384) Hsrc[(size_t)m * 384 + c] = f2bf(acc[i]);
        else if (c < 759) Cdst[(size_t)m * 375 + (c - 384)] = acc[i] + bpre_l[c - 384];
        else if (c < 834) Xpart[(size_t)m * 75 + (c - 759)] = acc[i];
      }
    }
  }
}

// ---------------- fused: gather/aggregate + per-tower MFMA post + scaler combine + lin GEMM ----------------
// 8 nodes / block, 256 threads (4 waves), A_s = 25.7 KB -> high occupancy.
// A layout (bf16): [node][t*320 + f*4 + agg], agg = {mean,min,max,std}; k pads [300,320) zeroed.
__global__ __launch_bounds__(256) void k_agg(const unsigned short* __restrict__ Hsrc,
                                             const float* __restrict__ Cdst,
                                             const int* __restrict__ off,
                                             const unsigned int* __restrict__ cpack,
                                             const float* __restrict__ etab_l,
                                             const unsigned short* __restrict__ WcombT_l,
                                             const unsigned short* __restrict__ WlinT_l,
                                             const float* __restrict__ amp,
                                             const float* __restrict__ invamp,
                                             const float* __restrict__ Xpart,
                                             const float* __restrict__ zb_l,
                                             float* __restrict__ Z) {
  __shared__ __align__(16) unsigned short A_s[8 * 1608];   // 25728 B; later aliased as Out f32[8][256] + Cb bf16[8][104]
  int tid = threadIdx.x;
  int w = tid >> 6, lane = tid & 63;
  int l15 = lane & 15, l4 = lane >> 4;
  int n0 = blockIdx.x * 8;

  // zero only the K-pads [300,320) of each (node,tower)
  for (int idx = tid; idx < 400; idx += 256) {
    int n = idx / 50; int r = idx - n * 50; int t = r / 10; int j = r - t * 10;
    *((unsigned int*)&A_s[n * 1608 + t * 320 + 300] + j) = 0u;
  }

  // ---- edge gather phase: each wave owns 2 nodes ----
  int c0 = lane * 6;           // channels c0..c0+5 (c<375 valid)
  int lane3 = lane * 3;
  for (int r = 0; r < 2; ++r) {
    int nl = w * 2 + r;
    int g = n0 + nl;
    int e0 = off[g], e1 = off[g + 1];
    float s6[6] = {0,0,0,0,0,0}, q6[6] = {0,0,0,0,0,0};
    float mn6[6], mx6[6];
    #pragma unroll
    for (int i = 0; i < 6; ++i) { mn6[i] = 3.402823466e+38f; mx6[i] = -3.402823466e+38f; }
    for (int e = e0; e < e1; ++e) {
      unsigned int pk = cpack[e];
      unsigned int sidx = pk & 0xFFFFu;
      unsigned int a = pk >> 16;
      const unsigned int* hp = (const unsigned int*)Hsrc + (size_t)sidx * 192 + lane3;
      unsigned int u0 = hp[0], u1 = hp[1], u2 = hp[2];
      const float2* ep = (const float2*)(etab_l + a * 384 + c0);
      float2 ea = ep[0], eb = ep[1], ec = ep[2];
      float v[6] = { bflo(u0), bfhi(u0), bflo(u1), bfhi(u1), bflo(u2), bfhi(u2) };
      float ee[6] = { ea.x, ea.y, eb.x, eb.y, ec.x, ec.y };
      #pragma unroll
      for (int i = 0; i < 6; ++i) {
        float q = v[i] + ee[i];
        s6[i] += q;
        q6[i] = fmaf(q, q, q6[i]);
        mn6[i] = fminf(mn6[i], q);
        mx6[i] = fmaxf(mx6[i], q);
      }
    }
    int d = e1 - e0;
    float inv = (d > 0) ? (1.0f / (float)d) : 0.0f;
    #pragma unroll
    for (int i = 0; i < 6; ++i) {
      int c = c0 + i;
      if (c < 375) {
        float mean, mnv, mxv, sd;
        if (d > 0) {
          float cd = Cdst[(size_t)g * 375 + c];
          float mu = s6[i] * inv;
          mean = cd + mu;
          mnv = cd + mn6[i];
          mxv = cd + mx6[i];
          sd = sqrtf(fmaxf(q6[i] * inv - mu * mu, 0.0f) + 1e-5f);
        } else { mean = 0.0f; mnv = 0.0f; mxv = 0.0f; sd = 0.0031622776601683794f; }
        int t = c / 75, f = c - t * 75;
        uint2 pk2;
        pk2.x = (unsigned int)f2bf(mean) | ((unsigned int)f2bf(mnv) << 16);
        pk2.y = (unsigned int)f2bf(mxv) | ((unsigned int)f2bf(sd) << 16);
        *(uint2*)&A_s[nl * 1608 + t * 320 + f * 4] = pk2;
      }
    }
  }
  __syncthreads();

  // ---- per-tower MFMA: [8(16) nodes x 320] @ [320 x 16 cols], 15 tasks over 4 waves ----
  f4_t accs[4];
  #pragma unroll
  for (int r = 0; r < 4; ++r) {
    int task = w + r * 4;
    f4_t acc = {0.f, 0.f, 0.f, 0.f};
    if (task < 15) {
      int t = task % 5, nf = task / 5;
      const unsigned short* ap = &A_s[(l15 & 7) * 1608 + t * 320 + l4 * 8];
      const unsigned short* wp = WcombT_l + (size_t)(t * 48 + nf * 16 + l15) * 320 + l4 * 8;
      #pragma unroll
      for (int ks = 0; ks < 10; ++ks) {
        bf8_t av = *(const bf8_t*)(ap + ks * 32);
        bf8_t bv = *(const bf8_t*)(wp + ks * 32);
        acc = __builtin_amdgcn_mfma_f32_16x16x32_bf16(av, bv, acc, 0, 0, 0);
      }
    }
    accs[r] = acc;
  }
  __syncthreads();   // all A_s reads done -> safe to alias

  // ---- exchange: Out f32 [8][256] aliased over A_s ----
  float* Out = (float*)A_s;
  #pragma unroll
  for (int r = 0; r < 4; ++r) {
    int task = w + r * 4;
    if (task < 15) {
      int t = task % 5, nf = task / 5;
      #pragma unroll
      for (int i = 0; i < 4; ++i) {
        int row = l4 * 4 + i;
        if (row < 8) Out[row * 256 + t * 48 + nf * 16 + l15] = accs[r][i];
      }
    }
  }
  __syncthreads();

  // ---- scaler combine -> Cb bf16 [8][104] (aliased after Out region) ----
  unsigned short* Cb = (unsigned short*)((char*)A_s + 8192);
  for (int item = tid; item < 8 * 104; item += 256) {
    int n = item / 104, o = item - (item / 104) * 104;
    unsigned short v = 0;
    if (o < 75) {
      int t = o / 15, jj = o - (o / 15) * 15;
      int g = n0 + n;
      const float* ob = Out + n * 256 + t * 48;
      float cv = ob[jj] + amp[g] * ob[15 + jj] + invamp[g] * ob[30 + jj];
      v = f2bf(cv);
    }
    Cb[n * 104 + o] = v;
  }
  __syncthreads();

  // ---- lin GEMM: Z = Cb @ Wlin + Xpart + zb  (K=96, 5 col-frags over 4 waves) ----
  #pragma unroll
  for (int r = 0; r < 2; ++r) {
    int nf = w + r * 4;
    if (nf < 5) {
      int cc = nf * 16 + l15;
      f4_t acc = {0.f, 0.f, 0.f, 0.f};
      const unsigned short* ap2 = Cb + (l15 & 7) * 104;
      const unsigned short* bp2 = WlinT_l + (size_t)cc * 96;
      #pragma unroll
      for (int ks = 0; ks < 3; ++ks) {
        bf8_t av = *(const bf8_t*)(ap2 + ks * 32 + l4 * 8);
        bf8_t bv = *(const bf8_t*)(bp2 + ks * 32 + l4 * 8);
        acc = __builtin_amdgcn_mfma_f32_16x16x32_bf16(av, bv, acc, 0, 0, 0);
      }
      if (cc < 75) {
        #pragma unroll
        for (int i = 0; i < 4; ++i) {
          int row = l4 * 4 + i;
          if (row < 8) {
            int g = n0 + row;
            Z[(size_t)g * 75 + cc] = acc[i] + Xpart[(size_t)g * 75 + cc] + zb_l[cc];
          }
        }
      }
    }
  }
}

// ---------------- batchnorm ----------------
#define BN_BLOCKS 256
#define BN_ROWS 196
__global__ __launch_bounds__(256) void k_bnstats(const float* __restrict__ Z, float* __restrict__ partial) {
  __shared__ float sArr[225];
  __shared__ float qArr[225];
  int tid = threadIdx.x;
  int r0 = blockIdx.x * BN_ROWS;
  int r1 = r0 + BN_ROWS; if (r1 > NN) r1 = NN;
  float s = 0.0f, q = 0.0f;
  if (tid < 225) {
    int rr = tid / 75, c = tid - rr * 75;
    for (int r = r0 + rr; r < r1; r += 3) {
      float v = Z[(size_t)r * 75 + c];
      s += v; q += v * v;
    }
    sArr[tid] = s; qArr[tid] = q;
  }
  __syncthreads();
  if (tid < 75) {
    float S = sArr[tid] + sArr[75 + tid] + sArr[150 + tid];
    float Q = qArr[tid] + qArr[75 + tid] + qArr[150 + tid];
    partial[blockIdx.x * 150 + tid] = S;
    partial[blockIdx.x * 150 + 75 + tid] = Q;
  }
}

__global__ void k_bnfinal(const float* __restrict__ partial, float* __restrict__ musig) {
  int c = threadIdx.x;
  if (c < 75) {
    float S = 0.0f, Q = 0.0f;
    for (int b = 0; b < BN_BLOCKS; ++b) { S += partial[b * 150 + c]; Q += partial[b * 150 + 75 + c]; }
    float mu = S * (1.0f / NN);
    float var = fmaxf(Q * (1.0f / NN) - mu * mu, 0.0f);
    musig[c] = mu;
    musig[75 + c] = 1.0f / sqrtf(var + 1e-5f);
  }
}

// BN apply + relu. layers 0-2: write hbf only; last layer: write hf32 only (for pooling).
__global__ void k_bnapply(const float* __restrict__ Z, const float* __restrict__ musig,
                          const float* __restrict__ gamma_l, const float* __restrict__ beta_l,
                          unsigned short* __restrict__ hbf, float* __restrict__ hf32, int last) {
  int i = blockIdx.x * 256 + threadIdx.x;
  if (i < NN * 96) {
    int n = i / 96, c = i - (i / 96) * 96;
    if (c < 75) {
      float v = (Z[(size_t)n * 75 + c] - musig[c]) * musig[75 + c];
      v = fmaxf(gamma_l[c] * v + beta_l[c], 0.0f);
      if (last) hf32[(size_t)n * 75 + c] = v;
      else hbf[i] = f2bf(v);
    } else if (!last) {
      hbf[i] = 0;
    }
  }
}

// ---------------- pool + MLP head ----------------
__global__ __launch_bounds__(128) void k_pool_mlp(const float* __restrict__ h, const int* __restrict__ batch,
                                                  const float* __restrict__ W1, const float* __restrict__ b1,
                                                  const float* __restrict__ W2, const float* __restrict__ b2,
                                                  const float* __restrict__ W3, const float* __restrict__ b3,
                                                  float* __restrict__ out) {
  __shared__ float pooled[75];
  __shared__ float z1[50];
  __shared__ float z2[25];
  __shared__ int se[2];
  int g = blockIdx.x, tid = threadIdx.x;
  if (tid < 2) {
    int target = g + tid;
    int lo = 0, hi = NN;
    while (lo < hi) { int mid = (lo + hi) >> 1; if (batch[mid] < target) lo = mid + 1; else hi = mid; }
    se[tid] = lo;
  }
  __syncthreads();
  int s = se[0], e = se[1];
  if (tid < 75) {
    float acc = 0.0f;
    for (int r = s; r < e; ++r) acc += h[(size_t)r * 75 + tid];
    pooled[tid] = acc;
  }
  __syncthreads();
  if (tid < 50) {
    float acc = b1[tid];
    for (int c = 0; c < 75; ++c) acc += pooled[c] * W1[c * 50 + tid];
    z1[tid] = fmaxf(acc, 0.0f);
  }
  __syncthreads();
  if (tid < 25) {
    float acc = b2[tid];
    for (int c = 0; c < 50; ++c) acc += z1[c] * W2[c * 25 + tid];
    z2[tid] = fmaxf(acc, 0.0f);
  }
  __syncthreads();
  if (tid == 0) {
    float acc = b3[0];
    for (int c = 0; c < 25; ++c) acc += z2[c] * W3[c];
    out[g] = acc;
  }
}

// ---------------- launch ----------------
extern "C" void kernel_launch(void* const* d_in, const int* in_sizes, int n_in,
                              void* d_out, int out_size, void* d_ws, size_t ws_size,
                              hipStream_t stream) {
  const int* x = (const int*)d_in[0];
  const int* ei = (const int*)d_in[1];
  const int* eattr = (const int*)d_in[2];
  const int* batch = (const int*)d_in[3];
  const float* node_emb = (const float*)d_in[4];
  const float* edge_emb = (const float*)d_in[5];
  const float* We = (const float*)d_in[6];
  const float* be = (const float*)d_in[7];
  const float* Wpre = (const float*)d_in[8];
  const float* bpre = (const float*)d_in[9];
  const float* Wpost = (const float*)d_in[10];
  const float* bpost = (const float*)d_in[11];
  const float* Wlin = (const float*)d_in[12];
  const float* blin = (const float*)d_in[13];
  const float* gamma = (const float*)d_in[14];
  const float* beta = (const float*)d_in[15];
  const float* W1 = (const float*)d_in[16];
  const float* b1 = (const float*)d_in[17];
  const float* W2 = (const float*)d_in[18];
  const float* b2 = (const float*)d_in[19];
  const float* W3 = (const float*)d_in[20];
  const float* b3 = (const float*)d_in[21];
  float* out = (float*)d_out;

  const int* src = ei;
  const int* dst = ei + NE;

  char* p = (char*)d_ws;
  auto alloc = [&](size_t bytes) { char* r = p; p += (bytes + 255) & ~(size_t)255; return r; };
  int* deg     = (int*)alloc((size_t)NN * 4);
  int* off     = (int*)alloc((size_t)(NN + 1) * 4);
  int* cursor  = (int*)alloc((size_t)NN * 4);
  unsigned int* cpack = (unsigned int*)alloc((size_t)NE * 4);
  float* amp    = (float*)alloc((size_t)NN * 4);
  float* invamp = (float*)alloc((size_t)NN * 4);
  unsigned short* hbf  = (unsigned short*)alloc((size_t)NN * 96 * 2);
  float* hf32          = (float*)alloc((size_t)NN * 75 * 4);
  unsigned short* Hsrc = (unsigned short*)alloc((size_t)NN * 384 * 2);
  float* Cdst          = (float*)alloc((size_t)NN * 375 * 4);
  float* Xpart         = (float*)alloc((size_t)NN * 75 * 4);
  float* Z             = (float*)alloc((size_t)NN * 75 * 4);
  unsigned short* B1T    = (unsigned short*)alloc((size_t)4 * 896 * 96 * 2);
  unsigned short* WcombT = (unsigned short*)alloc((size_t)4 * 5 * 48 * 320 * 2);
  unsigned short* WlinT  = (unsigned short*)alloc((size_t)4 * 80 * 96 * 2);
  float* WXlin = (float*)alloc((size_t)4 * 5625 * 4);
  float* zb    = (float*)alloc((size_t)4 * 75 * 4);
  float* etab  = (float*)alloc((size_t)4 * 4 * 384 * 4);
  float* bnpart = (float*)alloc((size_t)BN_BLOCKS * 150 * 4);
  float* musig  = (float*)alloc((size_t)150 * 4);

  hipMemsetAsync(deg, 0, (size_t)NN * 4, stream);
  k_deg<<<(NE + 255) / 256, 256, 0, stream>>>(dst, deg);
  k_scan<<<1, 1024, 0, stream>>>(deg, off);
  k_amp<<<(NN + 255) / 256, 256, 0, stream>>>(deg, off, amp, invamp, cursor);
  k_fill<<<(NE + 255) / 256, 256, 0, stream>>>(src, dst, eattr, cursor, cpack);
  k_embed<<<(NN * 96 + 255) / 256, 256, 0, stream>>>(x, node_emb, hbf);
  k_wxlin<<<4, 256, 0, stream>>>(Wpost, Wlin, WXlin);
  k_zb<<<4, 128, 0, stream>>>(bpost, blin, Wlin, zb);
  k_packB1<<<(4 * 896 * 96 + 255) / 256, 256, 0, stream>>>(Wpre, WXlin, B1T);
  k_packWcomb<<<(4 * 5 * 48 * 320 + 255) / 256, 256, 0, stream>>>(Wpost, WcombT);
  k_packWlin<<<(4 * 80 * 96 + 255) / 256, 256, 0, stream>>>(Wlin, WlinT);
  k_etab<<<16, 256, 0, stream>>>(edge_emb, We, be, Wpre, etab);

  dim3 g1(7, (NN + 63) / 64);
  for (int l = 0; l < NL; ++l) {
    k_gemm1<<<g1, 256, 0, stream>>>(hbf, B1T + (size_t)l * 896 * 96, bpre + l * 375, Hsrc, Cdst, Xpart);
    k_agg<<<NN / 8, 256, 0, stream>>>(Hsrc, Cdst, off, cpack,
                                      etab + (size_t)l * 4 * 384,
                                      WcombT + (size_t)l * 5 * 48 * 320,
                                      WlinT + (size_t)l * 80 * 96,
                                      amp, invamp, Xpart, zb + l * 75, Z);
    k_bnstats<<<BN_BLOCKS, 256, 0, stream>>>(Z, bnpart);
    k_bnfinal<<<1, 128, 0, stream>>>(bnpart, musig);
    k_bnapply<<<(NN * 96 + 255) / 256, 256, 0, stream>>>(Z, musig, gamma + l * 75, beta + l * 75, hbf, hf32, l == NL - 1);
  }
  k_pool_mlp<<<NG, 128, 0, stream>>>(hf32, batch, W1, b1, W2, b2, W3, b3, out);
}